// Round 3
// baseline (327.800 us; speedup 1.0000x reference)
//
#include <hip/hip_runtime.h>
#include <math.h>

#define TPB 192

// ---- LDS layout (float offsets), lifetime-overlaid; all vector-read bases
// provably aligned (sm is __align__(16); offsets mod 4 floats = 0 for float4,
// mod 2 for float2). Strides picked for bank spread (see per-phase notes).
// x   [0,784)       staged input; dead after dyn phase
// c1  [784,1840)    conv7 out [8][11][12] (stride 12: float2 rows; oc*132=4-bank step)
// f   [1840,1930)   conv5 out   (dead before dyn)
// h   [1932,1964)   fc1 out     (16B aligned; dead before dyn)
// y   [784,3384)    dyn out [10][13][20] (rows 16B aligned; rg2 step 40f=8 banks,
//                   ic step 260f=4 banks -> conflict-free float4 reads in conv2)
// k   [3384,3424)   dyn kernels
// P2  [3424,4724)   conv2 ic<5 half-partials [20][65]
// p3 [0,320) pf [324,474) a1 [480,530) z [532,542)  (over dead x)
#define OX    0
#define OC1   784
#define OF    1840
#define OH    1932
#define OY    784
#define OK2   3384
#define OP2   3424
#define OP3   0
#define OPF   324
#define OA1   480
#define OZ    532
#define SM_TOT 4724   // 18896 B -> 8 blocks/CU (LDS), wave cap 10 -> 8

// R3: issue-stream shrink. Rolled hot loops (icg/ic/t/j) with peeling so all
// register-array indices stay compile-time (rule #20); LDS re-layout for
// provable float2/float4 reads; fc paths vectorized. Target: fewer issued
// instructions + I$-resident code (~14KB vs ~40KB unrolled).
__global__ __launch_bounds__(TPB) void fused_forward(
    const float* __restrict__ x,
    const float* __restrict__ kf_w1, const float* __restrict__ kf_b1,
    const float* __restrict__ kf_w2, const float* __restrict__ kf_b2,
    const float* __restrict__ kf_fc1_w, const float* __restrict__ kf_fc1_b,
    const float* __restrict__ kf_fc2_w, const float* __restrict__ kf_fc2_b,
    const float* __restrict__ conv2_w, const float* __restrict__ conv2_b,
    const float* __restrict__ fc1_w, const float* __restrict__ fc1_b,
    const float* __restrict__ fc2_w, const float* __restrict__ fc2_b,
    float* __restrict__ out)
{
    __shared__ __align__(16) float sm[SM_TOT];
    const int tid = threadIdx.x;
    const int n = blockIdx.x;

    // ---- stage 0: stage x into LDS (float4) ----
    {
        const float4* xg = (const float4*)(x + (long long)n * 784);
        float4* d = (float4*)&sm[OX];
        #pragma unroll 1
        for (int i = tid; i < 196; i += TPB) d[i] = xg[i];
    }
    __syncthreads();

    // ---- conv7 (28->22) + pool (->11) + relu ----
    // oc = tid&7 -> 8-lane broadcast; x rows read as float2 (start 10h even).
    // t-loop rolled with t=0 / t=7 peeled (no branches, no OOB weight read).
    if (tid < 176) {
        int oc = tid & 7;
        int r  = tid >> 3;       // 0..21
        int py = r >> 1;         // 0..10
        int h  = r & 1;
        const int cc0 = 10 * h;  // even -> float2-aligned row start
        float c[2][12];
        #pragma unroll
        for (int r2 = 0; r2 < 2; ++r2)
            #pragma unroll
            for (int i = 0; i < 12; ++i) c[r2][i] = 0.f;
        float wc[7], wp[7];
        const float* wg = kf_w1 + oc * 49;
        #pragma unroll
        for (int i = 0; i < 7; ++i) wc[i] = wg[i];
        float row[18];
        // t = 0: only c[0] (ky=0)
        {
            const float2* xs = (const float2*)&sm[OX + (2 * py) * 28 + cc0];
            #pragma unroll
            for (int i = 0; i < 9; ++i) { float2 q = xs[i]; row[2*i] = q.x; row[2*i+1] = q.y; }
            #pragma unroll
            for (int kx = 0; kx < 7; ++kx)
                #pragma unroll
                for (int cc = 0; cc < 12; ++cc)
                    c[0][cc] = fmaf(wc[kx], row[cc + kx], c[0][cc]);
        }
        // t = 1..6: invariant entering iter t: wc = w row t-1 -> shift, load row t
        #pragma unroll 1
        for (int t = 1; t <= 6; ++t) {
            #pragma unroll
            for (int i = 0; i < 7; ++i) wp[i] = wc[i];
            const float* wn = wg + t * 7;
            #pragma unroll
            for (int i = 0; i < 7; ++i) wc[i] = wn[i];
            const float2* xs = (const float2*)&sm[OX + (2 * py + t) * 28 + cc0];
            #pragma unroll
            for (int i = 0; i < 9; ++i) { float2 q = xs[i]; row[2*i] = q.x; row[2*i+1] = q.y; }
            #pragma unroll
            for (int kx = 0; kx < 7; ++kx)
                #pragma unroll
                for (int cc = 0; cc < 12; ++cc) {
                    c[0][cc] = fmaf(wc[kx], row[cc + kx], c[0][cc]);
                    c[1][cc] = fmaf(wp[kx], row[cc + kx], c[1][cc]);
                }
        }
        // t = 7: only c[1] (ky=6 = wc after loop)
        {
            const float2* xs = (const float2*)&sm[OX + (2 * py + 7) * 28 + cc0];
            #pragma unroll
            for (int i = 0; i < 9; ++i) { float2 q = xs[i]; row[2*i] = q.x; row[2*i+1] = q.y; }
            #pragma unroll
            for (int kx = 0; kx < 7; ++kx)
                #pragma unroll
                for (int cc = 0; cc < 12; ++cc)
                    c[1][cc] = fmaf(wc[kx], row[cc + kx], c[1][cc]);
        }
        float b = kf_b1[oc];
        #pragma unroll
        for (int j = 0; j < 6; ++j) {
            float m = fmaxf(fmaxf(c[0][2 * j], c[0][2 * j + 1]),
                            fmaxf(c[1][2 * j], c[1][2 * j + 1]));
            sm[OC1 + oc * 132 + py * 12 + 5 * h + j] = fmaxf(m + b, 0.f);
        }
    }
    __syncthreads();

    // ---- conv5 (11->7) + pool (->3) + relu; ic-loop rolled, ky unrolled ----
    // c1 rows read as float2 (stride 12, 2px even). oc = tid%10 broadcast.
    if (tid < 90) {
        int oc = tid % 10, r = tid / 10;
        int py = r / 3, px = r % 3;
        float a00 = 0.f, a01 = 0.f, a10 = 0.f, a11 = 0.f;
        #pragma unroll 1
        for (int ic = 0; ic < 8; ++ic) {
            float w[25];
            const float* wg = kf_w2 + (oc * 8 + ic) * 25;
            #pragma unroll
            for (int i = 0; i < 25; ++i) w[i] = wg[i];
            const float* xb = &sm[OC1 + ic * 132 + 2 * py * 12 + 2 * px];
            float cur[6], nxt[6];
            {
                const float2* xr = (const float2*)xb;
                #pragma unroll
                for (int i = 0; i < 3; ++i) { float2 q = xr[i]; cur[2*i] = q.x; cur[2*i+1] = q.y; }
            }
            #pragma unroll
            for (int ky = 0; ky < 5; ++ky) {
                const float2* xr = (const float2*)(xb + (ky + 1) * 12);
                #pragma unroll
                for (int i = 0; i < 3; ++i) { float2 q = xr[i]; nxt[2*i] = q.x; nxt[2*i+1] = q.y; }
                #pragma unroll
                for (int kx = 0; kx < 5; ++kx) {
                    float wv = w[ky * 5 + kx];
                    a00 = fmaf(wv, cur[kx],     a00);
                    a01 = fmaf(wv, cur[kx + 1], a01);
                    a10 = fmaf(wv, nxt[kx],     a10);
                    a11 = fmaf(wv, nxt[kx + 1], a11);
                }
                #pragma unroll
                for (int i = 0; i < 6; ++i) cur[i] = nxt[i];
            }
        }
        float m = fmaxf(fmaxf(a00, a01), fmaxf(a10, a11)) + kf_b2[oc];
        sm[OF + oc * 9 + py * 3 + px] = fmaxf(m, 0.f);
    }
    __syncthreads();

    // ---- fc 90->32 + relu, then fc 32->40: both wave 0, no barrier between ----
    if (tid < 32) {
        float acc = kf_fc1_b[tid];
        const float2* wr = (const float2*)&kf_fc1_w[tid * 90];   // 90*4B*tid: 8B-aligned
        const float2* ff = (const float2*)&sm[OF];               // OF even
        #pragma unroll 1
        for (int i = 0; i < 45; ++i) {
            float2 wv = wr[i], fv = ff[i];
            acc = fmaf(wv.x, fv.x, acc);
            acc = fmaf(wv.y, fv.y, acc);
        }
        sm[OH + tid] = fmaxf(acc, 0.f);
    }
    if (tid < 40) {
        float acc = kf_fc2_b[tid];
        const float4* wr = (const float4*)&kf_fc2_w[tid * 32];   // 16B-aligned
        const float4* hh = (const float4*)&sm[OH];               // OH % 4 == 0
        #pragma unroll
        for (int i = 0; i < 8; ++i) {
            float4 wv = wr[i], hv = hh[i];
            acc = fmaf(wv.x, hv.x, acc);
            acc = fmaf(wv.y, hv.y, acc);
            acc = fmaf(wv.z, hv.z, acc);
            acc = fmaf(wv.w, hv.w, acc);
        }
        sm[OK2 + tid] = acc;
    }
    __syncthreads();

    // ---- dynamic 2x2 conv + pool + relu; oc = tid%10 broadcast; j rolled ----
    if (tid < 130) {
        int oc = tid % 10, py = tid / 10;
        const float4* kk = (const float4*)&sm[OK2 + oc * 4];     // OK2 % 4 == 0
        float4 kv = kk[0];
        float k0 = kv.x, k1 = kv.y, k2 = kv.z, k3 = kv.w;
        const float* x0 = &sm[OX + 2 * py * 28];
        const float* x1 = x0 + 28;
        const float* x2 = x0 + 56;
        float A0 = x0[0], A1 = x1[0], A2 = x2[0];
        float B0 = x0[1], B1 = x1[1], B2 = x2[1];
        float* yo = &sm[OY + oc * 260 + py * 20];
        #pragma unroll 1
        for (int j = 0; j < 13; ++j) {
            float C0 = x0[2 * j + 2], C1 = x1[2 * j + 2], C2 = x2[2 * j + 2];
            float c00 = A0 * k0 + B0 * k1 + A1 * k2 + B1 * k3;
            float c01 = B0 * k0 + C0 * k1 + B1 * k2 + C1 * k3;
            float c10 = A1 * k0 + B1 * k1 + A2 * k2 + B2 * k3;
            float c11 = B1 * k0 + C1 * k1 + B2 * k2 + C2 * k3;
            float m = fmaxf(fmaxf(c00, c01), fmaxf(c10, c11));
            yo[j] = fmaxf(m, 0.f);
            A0 = C0; A1 = C1; A2 = C2;
            B0 = x0[2 * j + 3]; B1 = x1[2 * j + 3]; B2 = x2[2 * j + 3];
        }
    }
    __syncthreads();

    // ---- conv2 5x5: only the 8x8 outputs the pool reads; icg rolled,
    // u fully unrolled (w[] indices stay compile-time). y rows: 3x float4.
    // h2=0 writes partials to P2; h2=1 keeps acc in regs across barrier.
    const int oc2 = tid % 20;
    const int q2  = tid / 20;
    const int h2  = q2 & 1;
    const int rg2 = q2 >> 1;
    float a2[2][8];
    if (tid < 160) {
        int r0 = 2 * rg2;
        #pragma unroll
        for (int r = 0; r < 2; ++r)
            #pragma unroll
            for (int i = 0; i < 8; ++i) a2[r][i] = 0.f;
        #pragma unroll 1
        for (int icg = 0; icg < 5; ++icg) {
            int ic = 5 * h2 + icg;
            float w[25];
            const float* wg = conv2_w + (oc2 * 10 + ic) * 25;
            #pragma unroll
            for (int i = 0; i < 25; ++i) w[i] = wg[i];
            const float* yb = &sm[OY + ic * 260 + r0 * 20];
            float row[12];
            #pragma unroll
            for (int u = 0; u < 6; ++u) {
                const float4* ys = (const float4*)(yb + u * 20);  // 16B-aligned
                #pragma unroll
                for (int i = 0; i < 3; ++i) {
                    float4 q = ys[i];
                    row[4*i] = q.x; row[4*i+1] = q.y; row[4*i+2] = q.z; row[4*i+3] = q.w;
                }
                #pragma unroll
                for (int rr = 0; rr < 2; ++rr) {
                    int ky = u - rr;
                    if (ky >= 0 && ky <= 4) {
                        #pragma unroll
                        for (int kx = 0; kx < 5; ++kx)
                            #pragma unroll
                            for (int cx = 0; cx < 8; ++cx)
                                a2[rr][cx] = fmaf(w[ky * 5 + kx], row[cx + kx], a2[rr][cx]);
                    }
                }
            }
        }
        if (h2 == 0) {
            int r0w = 2 * rg2;
            #pragma unroll
            for (int rr = 0; rr < 2; ++rr)
                #pragma unroll
                for (int cx = 0; cx < 8; ++cx)
                    sm[OP2 + oc2 * 65 + (r0w + rr) * 8 + cx] = a2[rr][cx];
        }
    }
    __syncthreads();

    // ---- combine halves + bias + pool + relu -> p3[20,4,4] (80 h2=1 threads) ----
    if (tid < 160 && h2 == 1) {
        float b = conv2_b[oc2];
        const float* p0 = &sm[OP2 + oc2 * 65 + (2 * rg2) * 8];
        #pragma unroll
        for (int px = 0; px < 4; ++px) {
            float c00 = b + a2[0][2 * px]     + p0[2 * px];
            float c01 = b + a2[0][2 * px + 1] + p0[2 * px + 1];
            float c10 = b + a2[1][2 * px]     + p0[8 + 2 * px];
            float c11 = b + a2[1][2 * px + 1] + p0[8 + 2 * px + 1];
            float m = fmaxf(fmaxf(c00, c01), fmaxf(c10, c11));
            sm[OP3 + oc2 * 16 + rg2 * 4 + px] = fmaxf(m, 0.f);
        }
    }
    __syncthreads();

    // ---- fc 320->50, 3-way k-split (112/112/96), float4 both sides ----
    if (tid < 150) {
        int g = tid / 50, o = tid % 50;
        int cnt = (g < 2) ? 28 : 24;
        const float4* wr4 = (const float4*)&fc1_w[o * 320 + g * 112];  // 16B-aligned
        const float4* pp4 = (const float4*)&sm[OP3 + g * 112];
        float acc = 0.f;
        #pragma unroll 1
        for (int i = 0; i < cnt; ++i) {
            float4 wv = wr4[i], pv = pp4[i];
            acc = fmaf(wv.x, pv.x, acc);
            acc = fmaf(wv.y, pv.y, acc);
            acc = fmaf(wv.z, pv.z, acc);
            acc = fmaf(wv.w, pv.w, acc);
        }
        sm[OPF + tid] = acc;
    }
    __syncthreads();

    // ---- tail: all wave 0, barrier-free (intra-wave LDS ordering) ----
    if (tid < 50) {
        float acc = fc1_b[tid];
        #pragma unroll
        for (int g = 0; g < 3; ++g) acc += sm[OPF + g * 50 + tid];
        sm[OA1 + tid] = fmaxf(acc, 0.f);
    }
    if (tid < 10) {
        float acc = fc2_b[tid];
        const float2* wr = (const float2*)&fc2_w[tid * 50];   // 50*4B*tid: 8B-aligned
        #pragma unroll
        for (int i = 0; i < 25; ++i) {
            float2 wv = wr[i];
            acc = fmaf(wv.x, sm[OA1 + 2 * i], acc);
            acc = fmaf(wv.y, sm[OA1 + 2 * i + 1], acc);
        }
        sm[OZ + tid] = acc;
    }
    if (tid < 10) {
        float m = sm[OZ + 0];
        #pragma unroll
        for (int i = 1; i < 10; ++i) m = fmaxf(m, sm[OZ + i]);
        float s = 0.f;
        #pragma unroll
        for (int i = 0; i < 10; ++i) s += expf(sm[OZ + i] - m);
        out[n * 10 + tid] = sm[OZ + tid] - m - logf(s);
    }
}

extern "C" void kernel_launch(void* const* d_in, const int* in_sizes, int n_in,
                              void* d_out, int out_size, void* d_ws, size_t ws_size,
                              hipStream_t stream) {
    const float* x        = (const float*)d_in[0];
    const float* kf_w1    = (const float*)d_in[1];
    const float* kf_b1    = (const float*)d_in[2];
    const float* kf_w2    = (const float*)d_in[3];
    const float* kf_b2    = (const float*)d_in[4];
    const float* kf_fc1_w = (const float*)d_in[5];
    const float* kf_fc1_b = (const float*)d_in[6];
    const float* kf_fc2_w = (const float*)d_in[7];
    const float* kf_fc2_b = (const float*)d_in[8];
    const float* conv2_w  = (const float*)d_in[9];
    const float* conv2_b  = (const float*)d_in[10];
    const float* fc1_w    = (const float*)d_in[11];
    const float* fc1_b    = (const float*)d_in[12];
    const float* fc2_w    = (const float*)d_in[13];
    const float* fc2_b    = (const float*)d_in[14];

    const int N = in_sizes[0] / 784;   // 8192

    fused_forward<<<N, TPB, 0, stream>>>(
        x, kf_w1, kf_b1, kf_w2, kf_b2, kf_fc1_w, kf_fc1_b, kf_fc2_w, kf_fc2_b,
        conv2_w, conv2_b, fc1_w, fc1_b, fc2_w, fc2_b, (float*)d_out);
}

// Round 4
// 275.133 us; speedup vs baseline: 1.1914x; 1.1914x over previous
//
#include <hip/hip_runtime.h>
#include <math.h>

#define TPB 192

// ---- LDS layout (float offsets), lifetime-overlaid; vector-read bases are
// provably aligned (sm __align__(16); float4 offsets %4==0, float2 %2==0).
// x   [0,784)       staged input; dead after dyn phase
// c1  [784,1840)    conv7 out [8][11][12] (stride-12 rows -> float2 reads)
// f   [1840,1930)   conv5 out  (inside future-y, dead before dyn)
// h   [1932,1964)   fc1 out    (16B aligned, dead before dyn)
// y   [784,3384)    dyn out [10][13][20] (rows 16B aligned -> float4 reads)
// k   [3384,3424)   dyn kernels — alive while y is written, so past y's end
// P2  [3424,4724)   conv2 ic<5 half-partials [20][65]
// p3 [0,320) pf [320,420) a1 [420,470) z [472,482)   (over dead x)
#define OX    0
#define OC1   784
#define OF    1840
#define OH    1932
#define OY    784
#define OK2   3384
#define OP2   3424
#define OP3   0
#define OPF   320
#define OA1   420
#define OZ    472
#define SM_TOT 4724   // 18896 B -> 8 blocks/CU (LDS); wave cap 10 -> 8. Non-binding.

// R4: R2's fully-unrolled schedule (R3's forced rolling serialized the stream:
// VALUBusy 67->56) + R3's vectorized LDS accesses (b32 -> b64/b128 halves the
// shared-LDS-pipe instruction count; 4 SIMDs share 1 LDS pipe, est. ~70% busy
// in R2 — the co-bottleneck with VALU). No #pragma unroll 1 anywhere hot.
__global__ __launch_bounds__(TPB) void fused_forward(
    const float* __restrict__ x,
    const float* __restrict__ kf_w1, const float* __restrict__ kf_b1,
    const float* __restrict__ kf_w2, const float* __restrict__ kf_b2,
    const float* __restrict__ kf_fc1_w, const float* __restrict__ kf_fc1_b,
    const float* __restrict__ kf_fc2_w, const float* __restrict__ kf_fc2_b,
    const float* __restrict__ conv2_w, const float* __restrict__ conv2_b,
    const float* __restrict__ fc1_w, const float* __restrict__ fc1_b,
    const float* __restrict__ fc2_w, const float* __restrict__ fc2_b,
    float* __restrict__ out)
{
    __shared__ __align__(16) float sm[SM_TOT];
    const int tid = threadIdx.x;
    const int n = blockIdx.x;

    // ---- stage 0: stage x into LDS (float4) ----
    {
        const float4* xg = (const float4*)(x + (long long)n * 784);
        float4* d = (float4*)&sm[OX];
        for (int i = tid; i < 196; i += TPB) d[i] = xg[i];
    }
    __syncthreads();

    // ---- conv7 (28->22) + pool (->11) + relu ----
    // oc = tid&7 -> 8-lane broadcast; x rows as float2 (start 10h even).
    if (tid < 176) {
        int oc = tid & 7;
        int r  = tid >> 3;
        int py = r >> 1;
        int h  = r & 1;
        const int cc0 = 10 * h;
        float c[2][12];
        #pragma unroll
        for (int r2 = 0; r2 < 2; ++r2)
            #pragma unroll
            for (int i = 0; i < 12; ++i) c[r2][i] = 0.f;
        float wc[7], wp[7];
        const float* wg = kf_w1 + oc * 49;
        #pragma unroll
        for (int i = 0; i < 7; ++i) wc[i] = wg[i];
        #pragma unroll
        for (int t = 0; t < 8; ++t) {
            const float2* xs = (const float2*)&sm[OX + (2 * py + t) * 28 + cc0];
            float row[18];
            #pragma unroll
            for (int i = 0; i < 9; ++i) { float2 q = xs[i]; row[2*i] = q.x; row[2*i+1] = q.y; }
            if (t <= 6) {
                #pragma unroll
                for (int kx = 0; kx < 7; ++kx)
                    #pragma unroll
                    for (int cc = 0; cc < 12; ++cc)
                        c[0][cc] = fmaf(wc[kx], row[cc + kx], c[0][cc]);
            }
            if (t >= 1) {
                #pragma unroll
                for (int kx = 0; kx < 7; ++kx)
                    #pragma unroll
                    for (int cc = 0; cc < 12; ++cc)
                        c[1][cc] = fmaf(wp[kx], row[cc + kx], c[1][cc]);
            }
            #pragma unroll
            for (int i = 0; i < 7; ++i) wp[i] = wc[i];
            if (t < 7) {
                const float* wn = wg + (t + 1) * 7;
                #pragma unroll
                for (int i = 0; i < 7; ++i) wc[i] = wn[i];
            }
        }
        float b = kf_b1[oc];
        #pragma unroll
        for (int j = 0; j < 6; ++j) {
            float m = fmaxf(fmaxf(c[0][2 * j], c[0][2 * j + 1]),
                            fmaxf(c[1][2 * j], c[1][2 * j + 1]));
            sm[OC1 + oc * 132 + py * 12 + 5 * h + j] = fmaxf(m + b, 0.f);
        }
    }
    __syncthreads();

    // ---- conv5 (11->7) + pool (->3) + relu; c1 rows as float2 (stride 12) ----
    if (tid < 90) {
        int oc = tid % 10, r = tid / 10;
        int py = r / 3, px = r % 3;
        float a00 = 0.f, a01 = 0.f, a10 = 0.f, a11 = 0.f;
        for (int ic = 0; ic < 8; ++ic) {
            float w[25];
            const float* wg = kf_w2 + (oc * 8 + ic) * 25;
            #pragma unroll
            for (int i = 0; i < 25; ++i) w[i] = wg[i];
            const float* xb = &sm[OC1 + ic * 132 + 2 * py * 12 + 2 * px];
            float cur[6], nxt[6];
            {
                const float2* xr = (const float2*)xb;
                #pragma unroll
                for (int i = 0; i < 3; ++i) { float2 q = xr[i]; cur[2*i] = q.x; cur[2*i+1] = q.y; }
            }
            #pragma unroll
            for (int ky = 0; ky < 5; ++ky) {
                const float2* xr = (const float2*)(xb + (ky + 1) * 12);
                #pragma unroll
                for (int i = 0; i < 3; ++i) { float2 q = xr[i]; nxt[2*i] = q.x; nxt[2*i+1] = q.y; }
                #pragma unroll
                for (int kx = 0; kx < 5; ++kx) {
                    float wv = w[ky * 5 + kx];
                    a00 = fmaf(wv, cur[kx],     a00);
                    a01 = fmaf(wv, cur[kx + 1], a01);
                    a10 = fmaf(wv, nxt[kx],     a10);
                    a11 = fmaf(wv, nxt[kx + 1], a11);
                }
                #pragma unroll
                for (int i = 0; i < 6; ++i) cur[i] = nxt[i];
            }
        }
        float m = fmaxf(fmaxf(a00, a01), fmaxf(a10, a11)) + kf_b2[oc];
        sm[OF + oc * 9 + py * 3 + px] = fmaxf(m, 0.f);
    }
    __syncthreads();

    // ---- fc 90->32 + relu, then fc 32->40: both wave 0, no barrier between ----
    if (tid < 32) {
        float acc = kf_fc1_b[tid];
        const float2* wr = (const float2*)&kf_fc1_w[tid * 90];   // 8B-aligned
        const float2* ff = (const float2*)&sm[OF];               // OF even
        for (int i = 0; i < 45; ++i) {
            float2 wv = wr[i], fv = ff[i];
            acc = fmaf(wv.x, fv.x, acc);
            acc = fmaf(wv.y, fv.y, acc);
        }
        sm[OH + tid] = fmaxf(acc, 0.f);
    }
    if (tid < 40) {
        float acc = kf_fc2_b[tid];
        const float4* wr = (const float4*)&kf_fc2_w[tid * 32];   // 16B-aligned
        const float4* hh = (const float4*)&sm[OH];               // OH % 4 == 0
        #pragma unroll
        for (int i = 0; i < 8; ++i) {
            float4 wv = wr[i], hv = hh[i];
            acc = fmaf(wv.x, hv.x, acc);
            acc = fmaf(wv.y, hv.y, acc);
            acc = fmaf(wv.z, hv.z, acc);
            acc = fmaf(wv.w, hv.w, acc);
        }
        sm[OK2 + tid] = acc;
    }
    __syncthreads();

    // ---- dynamic 2x2 conv + pool + relu; float2 pair reads (2j+2 even) ----
    if (tid < 130) {
        int oc = tid % 10, py = tid / 10;
        float4 kv = *(const float4*)&sm[OK2 + oc * 4];           // OK2 % 4 == 0
        float k0 = kv.x, k1 = kv.y, k2 = kv.z, k3 = kv.w;
        const float* x0 = &sm[OX + 2 * py * 28];
        const float* x1 = x0 + 28;
        const float* x2 = x0 + 56;
        float2 q0 = *(const float2*)&x0[0];
        float2 q1 = *(const float2*)&x1[0];
        float2 q2 = *(const float2*)&x2[0];
        float A0 = q0.x, B0 = q0.y;
        float A1 = q1.x, B1 = q1.y;
        float A2 = q2.x, B2 = q2.y;
        float* yo = &sm[OY + oc * 260 + py * 20];
        #pragma unroll
        for (int j = 0; j < 13; ++j) {
            float2 r0 = *(const float2*)&x0[2 * j + 2];   // (C, nextB)
            float2 r1 = *(const float2*)&x1[2 * j + 2];
            float2 r2 = *(const float2*)&x2[2 * j + 2];
            float C0 = r0.x, C1 = r1.x, C2 = r2.x;
            float c00 = A0 * k0 + B0 * k1 + A1 * k2 + B1 * k3;
            float c01 = B0 * k0 + C0 * k1 + B1 * k2 + C1 * k3;
            float c10 = A1 * k0 + B1 * k1 + A2 * k2 + B2 * k3;
            float c11 = B1 * k0 + C1 * k1 + B2 * k2 + C2 * k3;
            float m = fmaxf(fmaxf(c00, c01), fmaxf(c10, c11));
            yo[j] = fmaxf(m, 0.f);
            A0 = C0; A1 = C1; A2 = C2;
            B0 = r0.y; B1 = r1.y; B2 = r2.y;
        }
    }
    __syncthreads();

    // ---- conv2 5x5: only the 8x8 outputs the pool reads; y rows as 3x float4.
    // h2=0 writes partials to P2; h2=1 keeps acc in regs across barrier.
    const int oc2 = tid % 20;
    const int q2i = tid / 20;
    const int h2  = q2i & 1;
    const int rg2 = q2i >> 1;
    float a2[2][8];
    if (tid < 160) {
        int r0 = 2 * rg2;
        #pragma unroll
        for (int r = 0; r < 2; ++r)
            #pragma unroll
            for (int i = 0; i < 8; ++i) a2[r][i] = 0.f;
        for (int icg = 0; icg < 5; ++icg) {
            int ic = 5 * h2 + icg;
            float w[25];
            const float* wg = conv2_w + (oc2 * 10 + ic) * 25;
            #pragma unroll
            for (int i = 0; i < 25; ++i) w[i] = wg[i];
            const float* yb = &sm[OY + ic * 260 + r0 * 20];
            float row[12];
            #pragma unroll
            for (int u = 0; u < 6; ++u) {
                const float4* ys = (const float4*)(yb + u * 20);  // 16B-aligned
                #pragma unroll
                for (int i = 0; i < 3; ++i) {
                    float4 q = ys[i];
                    row[4*i] = q.x; row[4*i+1] = q.y; row[4*i+2] = q.z; row[4*i+3] = q.w;
                }
                #pragma unroll
                for (int rr = 0; rr < 2; ++rr) {
                    int ky = u - rr;
                    if (ky >= 0 && ky <= 4) {
                        #pragma unroll
                        for (int kx = 0; kx < 5; ++kx)
                            #pragma unroll
                            for (int cx = 0; cx < 8; ++cx)
                                a2[rr][cx] = fmaf(w[ky * 5 + kx], row[cx + kx], a2[rr][cx]);
                    }
                }
            }
        }
        if (h2 == 0) {
            int r0w = 2 * rg2;
            #pragma unroll
            for (int rr = 0; rr < 2; ++rr)
                #pragma unroll
                for (int cx = 0; cx < 8; ++cx)
                    sm[OP2 + oc2 * 65 + (r0w + rr) * 8 + cx] = a2[rr][cx];
        }
    }
    __syncthreads();

    // ---- combine halves + bias + pool + relu -> p3[20,4,4] (80 h2=1 threads) ----
    if (tid < 160 && h2 == 1) {
        float b = conv2_b[oc2];
        const float* p0 = &sm[OP2 + oc2 * 65 + (2 * rg2) * 8];
        #pragma unroll
        for (int px = 0; px < 4; ++px) {
            float c00 = b + a2[0][2 * px]     + p0[2 * px];
            float c01 = b + a2[0][2 * px + 1] + p0[2 * px + 1];
            float c10 = b + a2[1][2 * px]     + p0[8 + 2 * px];
            float c11 = b + a2[1][2 * px + 1] + p0[8 + 2 * px + 1];
            float m = fmaxf(fmaxf(c00, c01), fmaxf(c10, c11));
            sm[OP3 + oc2 * 16 + rg2 * 4 + px] = fmaxf(m, 0.f);
        }
    }
    __syncthreads();

    // ---- fc 320->50, 2-way k-split (100 threads, 40 float4 each, uniform) ----
    if (tid < 100) {
        int g = tid / 50, o = tid % 50;
        const float4* wr4 = (const float4*)&fc1_w[o * 320 + g * 160];  // 16B-aligned
        const float4* pp4 = (const float4*)&sm[OP3 + g * 160];
        float acc = 0.f;
        for (int i = 0; i < 40; ++i) {
            float4 wv = wr4[i], pv = pp4[i];
            acc = fmaf(wv.x, pv.x, acc);
            acc = fmaf(wv.y, pv.y, acc);
            acc = fmaf(wv.z, pv.z, acc);
            acc = fmaf(wv.w, pv.w, acc);
        }
        sm[OPF + tid] = acc;
    }
    __syncthreads();

    // ---- tail: all wave 0, barrier-free (intra-wave LDS ordering) ----
    if (tid < 50) {
        float acc = fc1_b[tid] + sm[OPF + tid] + sm[OPF + 50 + tid];
        sm[OA1 + tid] = fmaxf(acc, 0.f);
    }
    if (tid < 10) {
        float acc = fc2_b[tid];
        const float2* wr = (const float2*)&fc2_w[tid * 50];   // 8B-aligned
        #pragma unroll
        for (int i = 0; i < 25; ++i) {
            float2 wv = wr[i];
            acc = fmaf(wv.x, sm[OA1 + 2 * i], acc);
            acc = fmaf(wv.y, sm[OA1 + 2 * i + 1], acc);
        }
        sm[OZ + tid] = acc;
    }
    if (tid < 10) {
        float m = sm[OZ + 0];
        #pragma unroll
        for (int i = 1; i < 10; ++i) m = fmaxf(m, sm[OZ + i]);
        float s = 0.f;
        #pragma unroll
        for (int i = 0; i < 10; ++i) s += expf(sm[OZ + i] - m);
        out[n * 10 + tid] = sm[OZ + tid] - m - logf(s);
    }
}

extern "C" void kernel_launch(void* const* d_in, const int* in_sizes, int n_in,
                              void* d_out, int out_size, void* d_ws, size_t ws_size,
                              hipStream_t stream) {
    const float* x        = (const float*)d_in[0];
    const float* kf_w1    = (const float*)d_in[1];
    const float* kf_b1    = (const float*)d_in[2];
    const float* kf_w2    = (const float*)d_in[3];
    const float* kf_b2    = (const float*)d_in[4];
    const float* kf_fc1_w = (const float*)d_in[5];
    const float* kf_fc1_b = (const float*)d_in[6];
    const float* kf_fc2_w = (const float*)d_in[7];
    const float* kf_fc2_b = (const float*)d_in[8];
    const float* conv2_w  = (const float*)d_in[9];
    const float* conv2_b  = (const float*)d_in[10];
    const float* fc1_w    = (const float*)d_in[11];
    const float* fc1_b    = (const float*)d_in[12];
    const float* fc2_w    = (const float*)d_in[13];
    const float* fc2_b    = (const float*)d_in[14];

    const int N = in_sizes[0] / 784;   // 8192

    fused_forward<<<N, TPB, 0, stream>>>(
        x, kf_w1, kf_b1, kf_w2, kf_b2, kf_fc1_w, kf_fc1_b, kf_fc2_w, kf_fc2_b,
        conv2_w, conv2_b, fc1_w, fc1_b, fc2_w, fc2_b, (float*)d_out);
}